// Round 6
// baseline (17.248 us; speedup 1.0000x reference)
//
#include <hip/hip_runtime.h>
#include <math.h>

#define B_ 2
#define N_ 512
#define C_ 32
#define H_ 200
#define W_ 200
#define HW_ (H_*W_)
#define THRESH_ 0.05f
#define OUT_BEV (B_*C_*H_*W_)
#define NSEG 4                    // 4 waves/block, 128 gaussians each
#define TILES_PER_B 625           // 25x25 tiles of 8x8
#define LOG2E 1.4426950408889634f
#define LN2   0.6931471805599453f

typedef float v2f __attribute__((ext_vector_type(2)));

// Per-lane gaussian param compute + exact-ellipse-bbox tile-overlap test.
// q0 = (mu_u, mu_v, a2, b2), q1 = (c2, opac, thr2, pad); log2-domain quad.
__device__ __forceinline__ bool pcompute(
    const float* __restrict__ m3, const float* __restrict__ cv,
    const float* __restrict__ opc, int i,
    float tu0, float tu1, float tv0, float tv1, float4& q0, float4& q1)
{
    float x  = m3[i*3 + 0];
    float y  = m3[i*3 + 1];
    float c0 = cv[i*6 + 0];
    float c1 = cv[i*6 + 1];
    float c3 = cv[i*6 + 3];
    float op = opc[i];
    float mu_u = 100.0f - 100.0f * y;
    float mu_v = 100.0f - 100.0f * x;
    float Cuu = 10000.0f * c3 + 0.3f;
    float Cvv = 10000.0f * c0 + 0.3f;
    float Cuv = 10000.0f * c1;
    float det = Cuu * Cvv - Cuv * Cuv;
    bool valid = det > 0.0f;
    float opac = (op > THRESH_) ? op : 0.0f;
    if (!valid) opac = 0.0f;
    float inv_det = valid ? (1.0f / det) : 0.0f;
    float a2 = -0.5f * LOG2E * (Cvv * inv_det);
    float b2 = -0.5f * LOG2E * (Cuu * inv_det);
    float c2 =  LOG2E * (Cuv * inv_det);
    float thr2 = 3.0e38f;
    bool ov = false;
    if (opac > 0.0f) {
        float r2 = log2f(255.0f * opac);          // > 0 since opac > 0.05
        thr2 = -r2;
        float rn = LN2 * r2;
        float du_max = sqrtf(fmaxf(2.0f * rn * Cuu, 0.0f)) + 1.0e-3f;
        float dv_max = sqrtf(fmaxf(2.0f * rn * Cvv, 0.0f)) + 1.0e-3f;
        ov = (mu_u - du_max <= tu1) & (mu_u + du_max >= tu0) &
             (mu_v - dv_max <= tv1) & (mu_v + dv_max >= tv0);
    }
    q0 = make_float4(mu_u, mu_v, a2, b2);
    q1 = make_float4(c2, opac, thr2, 0.0f);
    return ov;
}

// Blocks 0..1249: one 8x8 tile (4 waves x 128-gaussian ordered segments,
// LDS-compacted hit list + counted unrolled hit loop). Block 1250: count.
__global__ __launch_bounds__(256, 5) void render_kernel(
    const float* __restrict__ features,   // [B,N,C]
    const float* __restrict__ means3D,    // [B,N,3]
    const float* __restrict__ cov3D,      // [B,N,6]
    const float* __restrict__ opacities,  // [B,N,1]
    float* __restrict__ out)              // [B,C,H,W] + 1 scalar
{
    __shared__ float s_T[NSEG][64];            // 1 KB
    __shared__ float s_W[NSEG * 64];           // 1 KB
    __shared__ float4 u_mem[NSEG * 128 * 2];   // 16 KB union: hit params | s_acc
    float4* s_hit = u_mem;
    float (*s_acc)[16][64] = (float (*)[16][64])u_mem;   // [NSEG][16][64]

    int blk = blockIdx.x;
    int tid = threadIdx.x;

    if (blk == B_ * TILES_PER_B) {             // ---- count-only block ----
        int cnt = ((opacities[tid]       > THRESH_) ? 1 : 0)
                + ((opacities[tid + 256] > THRESH_) ? 1 : 0)
                + ((opacities[tid + 512] > THRESH_) ? 1 : 0)
                + ((opacities[tid + 768] > THRESH_) ? 1 : 0);
        for (int off = 32; off > 0; off >>= 1) cnt += __shfl_down(cnt, off);
        int* s_red = (int*)s_W;
        if ((tid & 63) == 0) s_red[tid >> 6] = cnt;
        __syncthreads();
        if (tid == 0)
            out[OUT_BEV] = (float)(s_red[0] + s_red[1] + s_red[2] + s_red[3]) * 0.5f;
        return;
    }

    int b  = blk / TILES_PER_B;
    int t  = blk - b * TILES_PER_B;
    int tu = t / 25;
    int tv = t - tu * 25;
    int wave = __builtin_amdgcn_readfirstlane(tid >> 6);   // uniform
    int lane = tid & 63;

    float tu0 = (float)(tu * 8), tu1 = tu0 + 7.0f;
    float tv0 = (float)(tv * 8), tv1 = tv0 + 7.0f;

    // ---- per-lane params for the wave's two 64-gaussian halves ----
    float4 qA0, qA1, qB0, qB1;
    int i0 = b * N_ + wave * 128 + lane;
    bool ovA = pcompute(means3D, cov3D, opacities, i0,      tu0, tu1, tv0, tv1, qA0, qA1);
    bool ovB = pcompute(means3D, cov3D, opacities, i0 + 64, tu0, tu1, tv0, tv1, qB0, qB1);
    unsigned long long m0 = __ballot(ovA);
    unsigned long long m1 = __ballot(ovB);

    // ---- order-preserving compaction of hit params into LDS slots ----
    int sbase = wave * 256;                    // float4 units (128 slots * 2)
    {
        int posA = __builtin_amdgcn_mbcnt_hi((unsigned)(m0 >> 32),
                   __builtin_amdgcn_mbcnt_lo((unsigned)m0, 0));
        if (ovA) { int s = sbase + 2 * posA; s_hit[s] = qA0; s_hit[s + 1] = qA1; }
        int cA = __popcll(m0);
        int posB = __builtin_amdgcn_mbcnt_hi((unsigned)(m1 >> 32),
                   __builtin_amdgcn_mbcnt_lo((unsigned)m1, 0));
        if (ovB) { int s = sbase + 2 * (cA + posB); s_hit[s] = qB0; s_hit[s + 1] = qB1; }
    }

    int uu = tu * 8 + (lane >> 3);
    int vv = tv * 8 + (lane & 7);
    float u = (float)uu, v = (float)vv;

    float T = 1.0f;
    v2f acc2[16];
#pragma unroll
    for (int i = 0; i < 16; ++i) acc2[i] = (v2f){0.0f, 0.0f};

    const float* featB = features + (size_t)b * (N_ * C_);
    int nh = __builtin_amdgcn_readfirstlane(__popcll(m0) + __popcll(m1));
    unsigned long long w0 = m0, w1 = m1;
    int nbase = wave * 128;

    // ---- counted, branchless, unrolled hit loop (ascending n = slot order) --
#pragma unroll 2
    for (int k = 0; k < nh; ++k) {
        float4 q0 = s_hit[sbase + 2 * k];      // broadcast ds_read
        float4 q1 = s_hit[sbase + 2 * k + 1];
        bool useA = (w0 != 0ull);
        unsigned long long m = useA ? w0 : w1;
        int j = __builtin_ctzll(m);
        int n = nbase + (useA ? j : 64 + j);
        if (useA) w0 &= w0 - 1; else w1 &= w1 - 1;
        n = __builtin_amdgcn_readfirstlane(n);
        const v2f* f2 = (const v2f*)(featB + (size_t)n * C_);   // uniform -> s_load
        float du = u - q0.x;
        float dv = v - q0.y;
        float pw = fmaf(q0.z * du, du, fmaf(q0.w * dv, dv, q1.x * (du * dv)));
        bool hit = (pw <= 0.0f) && (pw >= q1.z);
        float al = hit ? fminf(0.99f, q1.y * exp2f(pw)) : 0.0f;
        float wgt = T * al;
        v2f w2 = {wgt, wgt};
#pragma unroll
        for (int i = 0; i < 16; ++i)
            acc2[i] = __builtin_elementwise_fma(w2, f2[i], acc2[i]);
        T *= (1.0f - al);
    }

    // ---- combine: prefix transmittance + 2 channel-rounds through LDS ----
    s_T[wave][lane] = T;
    __syncthreads();                            // hit loops done; u_mem reusable

    {
        float Wg = 1.0f;
        for (int g = 0; g < wave; ++g) Wg *= s_T[g][lane];
        s_W[wave * 64 + lane] = Wg;
    }

    size_t obase = (size_t)b * C_ * HW_ + (size_t)(tu * 8) * W_ + (size_t)(tv * 8);
    size_t opix  = (size_t)(lane >> 3) * W_ + (lane & 7);
#pragma unroll
    for (int k = 0; k < 2; ++k) {
#pragma unroll
        for (int cc = 0; cc < 8; ++cc) {
            v2f a = acc2[k * 8 + cc];
            s_acc[wave][cc * 2][lane]     = a.x;
            s_acc[wave][cc * 2 + 1][lane] = a.y;
        }
        __syncthreads();                        // s_acc (and s_W on k==0) visible
        float vq[4];
#pragma unroll
        for (int q = 0; q < 4; ++q) {
            float s = 0.0f;
#pragma unroll
            for (int g = 0; g < NSEG; ++g)
                s = fmaf(s_W[g * 64 + lane], s_acc[g][wave * 4 + q][lane], s);
            vq[q] = s;
        }
#pragma unroll
        for (int q = 0; q < 4; ++q)
            out[obase + (size_t)(k * 16 + wave * 4 + q) * HW_ + opix] = vq[q];
        if (k == 0) __syncthreads();            // before round-1 overwrites s_acc
    }
}

extern "C" void kernel_launch(void* const* d_in, const int* in_sizes, int n_in,
                              void* d_out, int out_size, void* d_ws, size_t ws_size,
                              hipStream_t stream) {
    const float* features  = (const float*)d_in[0];
    const float* means3D   = (const float*)d_in[1];
    const float* cov3D     = (const float*)d_in[2];
    const float* opacities = (const float*)d_in[3];
    float* out = (float*)d_out;
    render_kernel<<<B_ * TILES_PER_B + 1, 256, 0, stream>>>(
        features, means3D, cov3D, opacities, out);
}